// Round 9
// baseline (81.713 us; speedup 1.0000x reference)
//
#include <hip/hip_runtime.h>
#include <hip/hip_fp16.h>
#include <math.h>

#define TY 4
#define TX 64
#define AH (TY + 6)   // 10 ang rows
#define AW (TX + 6)   // 70 ang cols
#define PH (TY + 3)   // 7  pooled rows
#define PW (TX + 3)   // 67 pooled cols
#define H 512
#define W 512
#define HW (H * W)
#define PDIM 513      // pooled grid 0..512

// LDS layout (bytes): same as R7
#define ANGX_OFF 0
#define ANG_OFF  21440
#define POOL_OFF 21440
#define SMEM_BYTES 36448

__device__ __forceinline__ unsigned short f2h(float f) {
    return __half_as_ushort(__float2half(f));
}
__device__ __forceinline__ float h2f_lo(unsigned int u) {
    return __half2float(__ushort_as_half((unsigned short)(u & 0xffffu)));
}
__device__ __forceinline__ float h2f_hi(unsigned int u) {
    return __half2float(__ushort_as_half((unsigned short)(u >> 16)));
}

// ---------- shared device code for stages 1-3 (writes s_pool) ----------
__device__ __forceinline__ void stages123(const float* __restrict__ xb,
                                          int x0, int y0, int tid,
                                          float4* s_angx, uint4* s_ang, float4* s_pool) {
    const float K1[4] = {0.25f, 0.75f, 0.75f, 0.25f};
    // Stage 1
    for (int i = tid; i < AH * AW; i += 256) {
        int ay = i / AW, ax = i - ay * AW;
        int gy = y0 - 3 + ay, gx = x0 - 3 + ax;
        float w0 = 0.f, w1 = 0.f;
        int bin = 0;
        if (gy >= 0 && gy < H && gx >= 0 && gx < W) {
            int gxm = gx - 1 < 0 ? 0 : gx - 1;
            int gxp_ = gx + 1 > W - 1 ? W - 1 : gx + 1;
            int gym = gy - 1 < 0 ? 0 : gy - 1;
            int gyp_ = gy + 1 > H - 1 ? H - 1 : gy + 1;
            float gxv = 0.5f * (xb[gy * W + gxp_] - xb[gy * W + gxm]);
            float gyv = 0.5f * (xb[gyp_ * W + gx] - xb[gym * W + gx]);
            float mag = __builtin_amdgcn_sqrtf(gxv * gxv + gyv * gyv + 1e-10f);
            float gxe = gxv + 1e-10f;
            float axv = fabsf(gxe), ayv = fabsf(gyv);
            float mn = fminf(axv, ayv), mx = fmaxf(axv, ayv);
            float t = mn * __builtin_amdgcn_rcpf(fmaxf(mx, 1e-30f));
            float t2 = t * t;
            float p = t * fmaf(t2, fmaf(t2, fmaf(t2, fmaf(t2,
                        fmaf(t2, -0.01492385f, 0.06704027f),
                        -0.14824684f), 0.2464268f), -0.4235113f), 1.2732106f);
            float q = (ayv > axv) ? (2.0f - p) : p;
            q = (gxe < 0.0f) ? (4.0f - q) : q;
            float o = (gyv < 0.0f) ? (0.0f - q) : q;
            float of = floorf(o);
            float wo1 = o - of;
            bin = ((int)of) & 7;
            w0 = (1.f - wo1) * mag;
            w1 = wo1 * mag;
        }
        unsigned short h0 = f2h(w0), h1 = f2h(w1);
        unsigned int pack01 = (unsigned int)h0 | ((unsigned int)h1 << 16);
        unsigned int ph0 = (unsigned int)h0 << 16;
        unsigned int pl1 = (unsigned int)h1;
        int j0 = bin >> 1;
        int j1 = ((bin + 1) & 7) >> 1;
        bool ev = (bin & 1) == 0;
        uint4 d;
        d.x = ev ? (j0 == 0 ? pack01 : 0u) : ((j0 == 0 ? ph0 : 0u) | (j1 == 0 ? pl1 : 0u));
        d.y = ev ? (j0 == 1 ? pack01 : 0u) : ((j0 == 1 ? ph0 : 0u) | (j1 == 1 ? pl1 : 0u));
        d.z = ev ? (j0 == 2 ? pack01 : 0u) : ((j0 == 2 ? ph0 : 0u) | (j1 == 2 ? pl1 : 0u));
        d.w = ev ? (j0 == 3 ? pack01 : 0u) : ((j0 == 3 ? ph0 : 0u) | (j1 == 3 ? pl1 : 0u));
        s_ang[i] = d;
    }
    __syncthreads();
    // Stage 2
    for (int i = tid; i < AH * PW; i += 256) {
        int ay = i / PW, pxl = i - ay * PW;
        float acc[8] = {0.f, 0.f, 0.f, 0.f, 0.f, 0.f, 0.f, 0.f};
        int base = ay * AW + pxl;
        #pragma unroll
        for (int v = 0; v < 4; ++v) {
            uint4 q = s_ang[base + v];
            float k = K1[v];
            acc[0] = fmaf(k, h2f_lo(q.x), acc[0]);
            acc[1] = fmaf(k, h2f_hi(q.x), acc[1]);
            acc[2] = fmaf(k, h2f_lo(q.y), acc[2]);
            acc[3] = fmaf(k, h2f_hi(q.y), acc[3]);
            acc[4] = fmaf(k, h2f_lo(q.z), acc[4]);
            acc[5] = fmaf(k, h2f_hi(q.z), acc[5]);
            acc[6] = fmaf(k, h2f_lo(q.w), acc[6]);
            acc[7] = fmaf(k, h2f_hi(q.w), acc[7]);
        }
        s_angx[(ay * 2 + 0) * PW + pxl] = make_float4(acc[0], acc[1], acc[2], acc[3]);
        s_angx[(ay * 2 + 1) * PW + pxl] = make_float4(acc[4], acc[5], acc[6], acc[7]);
    }
    __syncthreads();
    // Stage 3
    for (int i = tid; i < PH * PW * 2; i += 256) {
        int row = i / PW, pxl = i - row * PW;
        int pyl = row >> 1;
        float4 s = make_float4(0.f, 0.f, 0.f, 0.f);
        #pragma unroll
        for (int u = 0; u < 4; ++u) {
            float4 a = s_angx[((pyl + u) * 2 + (row & 1)) * PW + pxl];
            float k = K1[u];
            s.x = fmaf(k, a.x, s.x);
            s.y = fmaf(k, a.y, s.y);
            s.z = fmaf(k, a.z, s.z);
            s.w = fmaf(k, a.w, s.w);
        }
        bool valid = ((unsigned)(y0 - 1 + pyl) <= 512u) && ((unsigned)(x0 - 1 + pxl) <= 512u);
        if (!valid) s = make_float4(0.f, 0.f, 0.f, 0.f);
        s_pool[row * PW + pxl] = s;
    }
    __syncthreads();
}

// ---------- K1: pooled -> workspace [b][py][px][8] ----------
__global__ __launch_bounds__(256, 4) void sift_pool_kernel(const float* __restrict__ x,
                                                           float* __restrict__ ws) {
    __shared__ __align__(16) char smem[SMEM_BYTES];
    float4* s_angx = (float4*)(smem + ANGX_OFF);
    uint4*  s_ang  = (uint4*)(smem + ANG_OFF);
    float4* s_pool = (float4*)(smem + POOL_OFF);

    const int tid = threadIdx.x;
    const int x0 = blockIdx.x * TX;
    const int y0 = blockIdx.y * TY;
    const int b  = blockIdx.z;
    const float* __restrict__ xb = x + (size_t)b * HW;

    stages123(xb, x0, y0, tid, s_angx, s_ang, s_pool);

    // write pooled rows pyl 1..5, cols pxl 1..65 (dups at tile seams are benign)
    const size_t bbase = (size_t)b * PDIM * PDIM;
    for (int i = tid; i < 5 * 65 * 2; i += 256) {
        int dh = i & 1;
        int j = i >> 1;
        int pyl = 1 + j / 65;
        int pxl = 1 + j - (j / 65) * 65;
        int py = y0 - 1 + pyl;
        int px = x0 - 1 + pxl;
        if (py <= 512 && px <= 512) {
            float4 v = s_pool[(pyl * 2 + dh) * PW + pxl];
            *(float4*)(ws + (bbase + (size_t)py * PDIM + px) * 8 + dh * 4) = v;
        }
    }
}

// ---------- K2: barrier-free epilogue (R7 epilogue, ws-sourced) ----------
__global__ __launch_bounds__(256, 4) void sift_epi_kernel(const float* __restrict__ ws,
                                                          float* __restrict__ out) {
    const int tid = threadIdx.x;
    const int x0 = blockIdx.x * TX;
    const int y0 = blockIdx.y * TY;
    const int b  = blockIdx.z;
    const int w  = tid >> 6;
    const int l  = tid & 63;
    const int dh = l >> 5;
    const int tx = 32 * (w & 1) + (l & 31);
    const int xx = x0 + tx;
    const float* __restrict__ pb = ws + (size_t)b * PDIM * PDIM * 8 + dh * 4;

    #pragma unroll
    for (int pp = 0; pp < 2; ++pp) {
        const int ty = 2 * pp + (w >> 1);
        const int yy = y0 + ty;
        float4 r[16];
        float ssq = 0.f;
        #pragma unroll
        for (int ky = 0; ky < 4; ++ky) {
            int py = yy - 1 + ky;
            float my = ((unsigned)py <= 512u) ? 1.f : 0.f;
            int pyc = py < 0 ? 0 : (py > 512 ? 512 : py);
            #pragma unroll
            for (int kx = 0; kx < 4; ++kx) {
                int px = xx - 1 + kx;
                float mxm = ((unsigned)px <= 512u) ? 1.f : 0.f;
                int pxc = px < 0 ? 0 : (px > 512 ? 512 : px);
                float4 t = *(const float4*)(pb + ((size_t)pyc * PDIM + pxc) * 8);
                float m = my * mxm;
                t.x *= m; t.y *= m; t.z *= m; t.w *= m;
                r[ky * 4 + kx] = t;
                ssq = fmaf(t.x, t.x, fmaf(t.y, t.y, fmaf(t.z, t.z, fmaf(t.w, t.w, ssq))));
            }
        }
        ssq += __shfl_xor(ssq, 32, 64);
        float inv = __builtin_amdgcn_rsqf(fmaxf(ssq, 1e-24f));
        float su = 0.f;
        #pragma unroll
        for (int m = 0; m < 16; ++m) {
            float4 t = r[m];
            t.x = fminf(t.x * inv, 0.2f);
            t.y = fminf(t.y * inv, 0.2f);
            t.z = fminf(t.z * inv, 0.2f);
            t.w = fminf(t.w * inv, 0.2f);
            r[m] = t;
            su += (t.x + t.y) + (t.z + t.w);
        }
        su += __shfl_xor(su, 32, 64);
        float rs = __builtin_amdgcn_rcpf(fmaxf(su, 1e-12f));
        float* __restrict__ op = out + ((size_t)b * 128 + dh * 64) * (size_t)HW
                                     + (size_t)yy * W + xx;
        #pragma unroll
        for (int dd = 0; dd < 4; ++dd) {
            #pragma unroll
            for (int m = 0; m < 16; ++m) {
                float4 t = r[m];
                float comp = (dd == 0) ? t.x : (dd == 1) ? t.y : (dd == 2) ? t.z : t.w;
                float val = __builtin_amdgcn_sqrtf(fmaf(comp, rs, 1e-10f));
                op[(size_t)(dd * 16 + m) * HW] = val;
            }
        }
    }
}

// ---------- fallback: R7 fused kernel (if ws too small) ----------
__global__ __launch_bounds__(256, 4) void sift_fused_kernel(const float* __restrict__ x,
                                                            float* __restrict__ out) {
    __shared__ __align__(16) char smem[SMEM_BYTES];
    float4* s_angx = (float4*)(smem + ANGX_OFF);
    uint4*  s_ang  = (uint4*)(smem + ANG_OFF);
    float4* s_pool = (float4*)(smem + POOL_OFF);

    const int tid = threadIdx.x;
    const int x0 = blockIdx.x * TX;
    const int y0 = blockIdx.y * TY;
    const int b  = blockIdx.z;
    const float* __restrict__ xb = x + (size_t)b * HW;

    stages123(xb, x0, y0, tid, s_angx, s_ang, s_pool);

    const int w  = tid >> 6;
    const int l  = tid & 63;
    const int dh = l >> 5;
    const int tx = 32 * (w & 1) + (l & 31);
    const int xx = x0 + tx;

    #pragma unroll
    for (int pp = 0; pp < 2; ++pp) {
        const int ty = 2 * pp + (w >> 1);
        const int yy = y0 + ty;
        float4 r[16];
        float ssq = 0.f;
        #pragma unroll
        for (int ky = 0; ky < 4; ++ky) {
            #pragma unroll
            for (int kx = 0; kx < 4; ++kx) {
                float4 t = s_pool[((ty + ky) * 2 + dh) * PW + (tx + kx)];
                r[ky * 4 + kx] = t;
                ssq = fmaf(t.x, t.x, ssq);
                ssq = fmaf(t.y, t.y, ssq);
                ssq = fmaf(t.z, t.z, ssq);
                ssq = fmaf(t.w, t.w, ssq);
            }
        }
        ssq += __shfl_xor(ssq, 32, 64);
        float inv = __builtin_amdgcn_rsqf(fmaxf(ssq, 1e-24f));
        float su = 0.f;
        #pragma unroll
        for (int m = 0; m < 16; ++m) {
            float4 t = r[m];
            t.x = fminf(t.x * inv, 0.2f);
            t.y = fminf(t.y * inv, 0.2f);
            t.z = fminf(t.z * inv, 0.2f);
            t.w = fminf(t.w * inv, 0.2f);
            r[m] = t;
            su += (t.x + t.y) + (t.z + t.w);
        }
        su += __shfl_xor(su, 32, 64);
        float rs = __builtin_amdgcn_rcpf(fmaxf(su, 1e-12f));
        float* __restrict__ op = out + ((size_t)b * 128 + dh * 64) * (size_t)HW
                                     + (size_t)yy * W + xx;
        #pragma unroll
        for (int dd = 0; dd < 4; ++dd) {
            #pragma unroll
            for (int m = 0; m < 16; ++m) {
                float4 t = r[m];
                float comp = (dd == 0) ? t.x : (dd == 1) ? t.y : (dd == 2) ? t.z : t.w;
                float val = __builtin_amdgcn_sqrtf(fmaf(comp, rs, 1e-10f));
                op[(size_t)(dd * 16 + m) * HW] = val;
            }
        }
    }
}

extern "C" void kernel_launch(void* const* d_in, const int* in_sizes, int n_in,
                              void* d_out, int out_size, void* d_ws, size_t ws_size,
                              hipStream_t stream) {
    const float* x = (const float*)d_in[0];
    float* out = (float*)d_out;
    const int B = in_sizes[0] / (H * W);   // = 2
    dim3 grid(W / TX, H / TY, B);
    dim3 block(256);
    const size_t ws_need = (size_t)B * PDIM * PDIM * 8 * sizeof(float);
    if (ws_size >= ws_need) {
        float* ws = (float*)d_ws;
        hipLaunchKernelGGL(sift_pool_kernel, grid, block, 0, stream, x, ws);
        hipLaunchKernelGGL(sift_epi_kernel, grid, block, 0, stream, ws, out);
    } else {
        hipLaunchKernelGGL(sift_fused_kernel, grid, block, 0, stream, x, out);
    }
    (void)n_in; (void)out_size;
}

// Round 10
// 49.236 us; speedup vs baseline: 1.6596x; 1.6596x over previous
//
#include <hip/hip_runtime.h>
#include <hip/hip_fp16.h>
#include <math.h>

#define TY 4
#define TX 64
#define AH (TY + 6)   // 10 ang rows
#define AW (TX + 6)   // 70 ang cols
#define PH (TY + 3)   // 7  pooled rows
#define PW (TX + 3)   // 67 pooled cols
#define H 512
#define W 512
#define HW (H * W)

// LDS layout (bytes):
//   [0, 21440)        s_angx  f32 [AH][2][PW][4]    (10*2*67*16)
//   [21440, 32640)    s_ang   f16x8 [AH][AW]        (700*16)   -- dead after stage 2
//   [21440, 28944)    s_pool16 f16x4 [PH][2][PW]    (14*67*8)  -- aliases s_ang
#define ANGX_OFF 0
#define ANG_OFF  21440
#define POOL_OFF 21440
#define SMEM_BYTES 32640

__device__ __forceinline__ unsigned short f2h(float f) {
    return __half_as_ushort(__float2half(f));
}
__device__ __forceinline__ float h2f_lo(unsigned int u) {
    return __half2float(__ushort_as_half((unsigned short)(u & 0xffffu)));
}
__device__ __forceinline__ float h2f_hi(unsigned int u) {
    return __half2float(__ushort_as_half((unsigned short)(u >> 16)));
}

__global__ __launch_bounds__(256, 5) void sift_kernel(const float* __restrict__ x,
                                                      float* __restrict__ out) {
    __shared__ __align__(16) char smem[SMEM_BYTES];
    float4* s_angx  = (float4*)(smem + ANGX_OFF);   // [(ay*2+dh)*PW + pxl]
    uint4*  s_ang   = (uint4*)(smem + ANG_OFF);     // [ay*AW + ax], 8 ch f16
    uint2*  s_pool16= (uint2*)(smem + POOL_OFF);    // [(pyl*2+dh)*PW + pxl], 4 ch f16

    const int tid = threadIdx.x;
    const int x0 = blockIdx.x * TX;
    const int y0 = blockIdx.y * TY;
    const int b  = blockIdx.z;
    const float* __restrict__ xb = x + (size_t)b * HW;

    const float K1[4] = {0.25f, 0.75f, 0.75f, 0.25f};

    // ---- Stage 1: gradient + soft-bin (poly atan), packed f16x8 scatter ----
    for (int i = tid; i < AH * AW; i += 256) {
        int ay = i / AW, ax = i - ay * AW;
        int gy = y0 - 3 + ay, gx = x0 - 3 + ax;
        float w0 = 0.f, w1 = 0.f;
        int bin = 0;
        if (gy >= 0 && gy < H && gx >= 0 && gx < W) {
            int gxm = gx - 1 < 0 ? 0 : gx - 1;
            int gxp_ = gx + 1 > W - 1 ? W - 1 : gx + 1;
            int gym = gy - 1 < 0 ? 0 : gy - 1;
            int gyp_ = gy + 1 > H - 1 ? H - 1 : gy + 1;
            float gxv = 0.5f * (xb[gy * W + gxp_] - xb[gy * W + gxm]);
            float gyv = 0.5f * (xb[gyp_ * W + gx] - xb[gym * W + gx]);
            float mag = __builtin_amdgcn_sqrtf(gxv * gxv + gyv * gyv + 1e-10f);
            float gxe = gxv + 1e-10f;
            float axv = fabsf(gxe), ayv = fabsf(gyv);
            float mn = fminf(axv, ayv), mx = fmaxf(axv, ayv);
            float t = mn * __builtin_amdgcn_rcpf(fmaxf(mx, 1e-30f));
            float t2 = t * t;
            float p = t * fmaf(t2, fmaf(t2, fmaf(t2, fmaf(t2,
                        fmaf(t2, -0.01492385f, 0.06704027f),
                        -0.14824684f), 0.2464268f), -0.4235113f), 1.2732106f);
            float q = (ayv > axv) ? (2.0f - p) : p;
            q = (gxe < 0.0f) ? (4.0f - q) : q;
            float o = (gyv < 0.0f) ? (0.0f - q) : q;
            float of = floorf(o);
            float wo1 = o - of;
            bin = ((int)of) & 7;
            w0 = (1.f - wo1) * mag;
            w1 = wo1 * mag;
        }
        unsigned short h0 = f2h(w0), h1 = f2h(w1);
        unsigned int pack01 = (unsigned int)h0 | ((unsigned int)h1 << 16);
        unsigned int ph0 = (unsigned int)h0 << 16;
        unsigned int pl1 = (unsigned int)h1;
        int j0 = bin >> 1;
        int j1 = ((bin + 1) & 7) >> 1;
        bool ev = (bin & 1) == 0;
        uint4 d;
        d.x = ev ? (j0 == 0 ? pack01 : 0u) : ((j0 == 0 ? ph0 : 0u) | (j1 == 0 ? pl1 : 0u));
        d.y = ev ? (j0 == 1 ? pack01 : 0u) : ((j0 == 1 ? ph0 : 0u) | (j1 == 1 ? pl1 : 0u));
        d.z = ev ? (j0 == 2 ? pack01 : 0u) : ((j0 == 2 ? ph0 : 0u) | (j1 == 2 ? pl1 : 0u));
        d.w = ev ? (j0 == 3 ? pack01 : 0u) : ((j0 == 3 ? ph0 : 0u) | (j1 == 3 ? pl1 : 0u));
        s_ang[i] = d;
    }
    __syncthreads();

    // ---- Stage 2: horizontal 1D conv (f16 in, f32 out) ----
    for (int i = tid; i < AH * PW; i += 256) {
        int ay = i / PW, pxl = i - ay * PW;
        float acc[8] = {0.f, 0.f, 0.f, 0.f, 0.f, 0.f, 0.f, 0.f};
        int base = ay * AW + pxl;
        #pragma unroll
        for (int v = 0; v < 4; ++v) {
            uint4 q = s_ang[base + v];
            float k = K1[v];
            acc[0] = fmaf(k, h2f_lo(q.x), acc[0]);
            acc[1] = fmaf(k, h2f_hi(q.x), acc[1]);
            acc[2] = fmaf(k, h2f_lo(q.y), acc[2]);
            acc[3] = fmaf(k, h2f_hi(q.y), acc[3]);
            acc[4] = fmaf(k, h2f_lo(q.z), acc[4]);
            acc[5] = fmaf(k, h2f_hi(q.z), acc[5]);
            acc[6] = fmaf(k, h2f_lo(q.w), acc[6]);
            acc[7] = fmaf(k, h2f_hi(q.w), acc[7]);
        }
        s_angx[(ay * 2 + 0) * PW + pxl] = make_float4(acc[0], acc[1], acc[2], acc[3]);
        s_angx[(ay * 2 + 1) * PW + pxl] = make_float4(acc[4], acc[5], acc[6], acc[7]);
    }
    __syncthreads();

    // ---- Stage 3: vertical conv (f32) -> pooled, packed f16x4 + boundary zero ----
    for (int i = tid; i < PH * PW * 2; i += 256) {
        int row = i / PW, pxl = i - row * PW;   // row = pyl*2 + dh
        int pyl = row >> 1;
        float4 s = make_float4(0.f, 0.f, 0.f, 0.f);
        #pragma unroll
        for (int u = 0; u < 4; ++u) {
            float4 a = s_angx[((pyl + u) * 2 + (row & 1)) * PW + pxl];
            float k = K1[u];
            s.x = fmaf(k, a.x, s.x);
            s.y = fmaf(k, a.y, s.y);
            s.z = fmaf(k, a.z, s.z);
            s.w = fmaf(k, a.w, s.w);
        }
        bool valid = ((unsigned)(y0 - 1 + pyl) <= 512u) && ((unsigned)(x0 - 1 + pxl) <= 512u);
        if (!valid) s = make_float4(0.f, 0.f, 0.f, 0.f);
        uint2 pk;
        pk.x = (unsigned int)f2h(s.x) | ((unsigned int)f2h(s.y) << 16);
        pk.y = (unsigned int)f2h(s.z) | ((unsigned int)f2h(s.w) << 16);
        s_pool16[row * PW + pxl] = pk;
    }
    __syncthreads();

    // ---- Epilogue: 2 threads per pixel (channel halves), packed-f16 r cache ----
    const int w  = tid >> 6;
    const int l  = tid & 63;
    const int dh = l >> 5;
    const int tx = 32 * (w & 1) + (l & 31);
    const int xx = x0 + tx;

    #pragma unroll
    for (int pp = 0; pp < 2; ++pp) {
        const int ty = 2 * pp + (w >> 1);
        const int yy = y0 + ty;
        uint2 r[16];                 // 32 VGPR: 4 ch f16 per (ky,kx)
        float ssq = 0.f;
        #pragma unroll
        for (int ky = 0; ky < 4; ++ky) {
            #pragma unroll
            for (int kx = 0; kx < 4; ++kx) {
                uint2 q = s_pool16[((ty + ky) * 2 + dh) * PW + (tx + kx)];
                r[ky * 4 + kx] = q;
                float a0 = h2f_lo(q.x), a1 = h2f_hi(q.x);
                float a2 = h2f_lo(q.y), a3 = h2f_hi(q.y);
                ssq = fmaf(a0, a0, fmaf(a1, a1, fmaf(a2, a2, fmaf(a3, a3, ssq))));
            }
        }
        ssq += __shfl_xor(ssq, 32, 64);
        float inv = __builtin_amdgcn_rsqf(fmaxf(ssq, 1e-24f));
        float su = 0.f;
        #pragma unroll
        for (int m = 0; m < 16; ++m) {
            uint2 q = r[m];
            su += fminf(h2f_lo(q.x) * inv, 0.2f) + fminf(h2f_hi(q.x) * inv, 0.2f)
                + fminf(h2f_lo(q.y) * inv, 0.2f) + fminf(h2f_hi(q.y) * inv, 0.2f);
        }
        su += __shfl_xor(su, 32, 64);
        float rs = __builtin_amdgcn_rcpf(fmaxf(su, 1e-12f));
        // c = dh*64 + dd*16 + m ; plain stores through L2
        float* __restrict__ op = out + ((size_t)b * 128 + dh * 64) * (size_t)HW
                                     + (size_t)yy * W + xx;
        #pragma unroll
        for (int dd = 0; dd < 4; ++dd) {
            #pragma unroll
            for (int m = 0; m < 16; ++m) {
                uint2 q = r[m];
                float comp = (dd == 0) ? h2f_lo(q.x) : (dd == 1) ? h2f_hi(q.x)
                           : (dd == 2) ? h2f_lo(q.y) : h2f_hi(q.y);
                float u = fminf(comp * inv, 0.2f);
                float val = __builtin_amdgcn_sqrtf(fmaf(u, rs, 1e-10f));
                op[(size_t)(dd * 16 + m) * HW] = val;
            }
        }
    }
}

extern "C" void kernel_launch(void* const* d_in, const int* in_sizes, int n_in,
                              void* d_out, int out_size, void* d_ws, size_t ws_size,
                              hipStream_t stream) {
    const float* x = (const float*)d_in[0];
    float* out = (float*)d_out;
    const int B = in_sizes[0] / (H * W);   // = 2
    dim3 grid(W / TX, H / TY, B);
    dim3 block(256);
    hipLaunchKernelGGL(sift_kernel, grid, block, 0, stream, x, out);
    (void)n_in; (void)out_size; (void)d_ws; (void)ws_size;
}